// Round 10
// baseline (10907.481 us; speedup 1.0000x reference)
//
#include <hip/hip_runtime.h>
#include <hip/hip_bf16.h>

#define EPSF 1e-5f

typedef unsigned short u16;
typedef unsigned int   u32;
typedef __attribute__((ext_vector_type(8))) short short8;
typedef __attribute__((ext_vector_type(4))) float f32x4;

constexpr int B  = 256;
constexpr int T  = 128;
constexpr int H  = 1024;
constexpr int INNER = 3 * H;   // 3072
constexpr int BT = B * T;      // 32768
constexpr int NZ = 2 * H;      // 2048

__device__ inline u16 f2bf(float v) {
    u32 u = __float_as_uint(v);
    return (u16)((u + 0x7fffu + ((u >> 16) & 1u)) >> 16);
}
__device__ inline float bf2f(u16 h) { return __uint_as_float(((u32)h) << 16); }

// ---------- one-time: transpose fp32 [1024][3072] -> split bf16 [3072][1024] ----------
__global__ __launch_bounds__(256)
void transpose_split(const float* __restrict__ src, u16* __restrict__ dhi, u16* __restrict__ dlo)
{
    __shared__ float tile[32][33];
    const int tx = threadIdx.x & 31, ty = threadIdx.x >> 5;
    const int bx = blockIdx.x, by = blockIdx.y;
    #pragma unroll
    for (int i = 0; i < 4; ++i)
        tile[ty + i * 8][tx] = src[(size_t)(by * 32 + ty + i * 8) * INNER + bx * 32 + tx];
    __syncthreads();
    #pragma unroll
    for (int i = 0; i < 4; ++i) {
        int n = bx * 32 + ty + i * 8;
        int k = by * 32 + tx;
        float v = tile[tx][ty + i * 8];
        u16 hi = f2bf(v);
        dhi[(size_t)n * H + k] = hi;
        dlo[(size_t)n * H + k] = f2bf(v - bf2f(hi));
    }
}

// ---------- big GEMM: S1b = x @ W + bias (fp32 out), split-bf16 3-pass MFMA ----------
__global__ __launch_bounds__(256)
void gemm_s1(const float* __restrict__ Af,
             const u16* __restrict__ Bhi, const u16* __restrict__ Blo,
             const float* __restrict__ bias, float* __restrict__ C)
{
    constexpr int BM = 128, BN = 128, FM = 4, FN = 4;
    __shared__ char lds[(BM + BN) * 256];
    char* sAhi = lds;
    char* sAlo = lds + BM * 128;
    char* sBhi = lds + BM * 256;
    char* sBlo = lds + BM * 256 + BN * 128;

    const int tid = threadIdx.x;
    const int m0 = blockIdx.y * BM, n0 = blockIdx.x * BN;
    const int wid = tid >> 6, lane = tid & 63;
    const int wm = wid >> 1, wn = wid & 1;
    const int lr = lane & 15, kg = lane >> 4;

    f32x4 acc[FM][FN] = {};

    for (int k0 = 0; k0 < H; k0 += 64) {
        {
            constexpr int NC = BM * 16 / 256;
            #pragma unroll
            for (int i = 0; i < NC; ++i) {
                int c = tid + i * 256;
                int row = c >> 4, kc = c & 15;
                const float4 v = *(const float4*)(Af + (size_t)(m0 + row) * H + k0 + kc * 4);
                u16 h0 = f2bf(v.x), h1 = f2bf(v.y), h2 = f2bf(v.z), h3 = f2bf(v.w);
                u16 l0 = f2bf(v.x - bf2f(h0)), l1 = f2bf(v.y - bf2f(h1));
                u16 l2 = f2bf(v.z - bf2f(h2)), l3 = f2bf(v.w - bf2f(h3));
                uint2 hp, lp;
                hp.x = (u32)h0 | ((u32)h1 << 16); hp.y = (u32)h2 | ((u32)h3 << 16);
                lp.x = (u32)l0 | ((u32)l1 << 16); lp.y = (u32)l2 | ((u32)l3 << 16);
                int boff = row * 128 + ((((kc >> 1)) ^ (row & 7)) << 4) + ((kc & 1) << 3);
                *(uint2*)(sAhi + boff) = hp;
                *(uint2*)(sAlo + boff) = lp;
            }
        }
        {
            constexpr int NC = BN * 8 / 256;
            #pragma unroll
            for (int i = 0; i < NC; ++i) {
                int c = tid + i * 256;
                int row = c >> 3, kc = c & 7;
                int boff = row * 128 + ((kc ^ (row & 7)) << 4);
                *(float4*)(sBhi + boff) = *(const float4*)(Bhi + (size_t)(n0 + row) * H + k0 + kc * 8);
                *(float4*)(sBlo + boff) = *(const float4*)(Blo + (size_t)(n0 + row) * H + k0 + kc * 8);
            }
        }
        __syncthreads();

        #pragma unroll
        for (int ks = 0; ks < 2; ++ks) {
            short8 ah[FM], al[FM], bh[FN], bl[FN];
            #pragma unroll
            for (int mi = 0; mi < FM; ++mi) {
                int row = wm * FM * 16 + mi * 16 + lr;
                int off = row * 128 + ((((ks << 2) | kg) ^ (row & 7)) << 4);
                ah[mi] = *(const short8*)(sAhi + off);
                al[mi] = *(const short8*)(sAlo + off);
            }
            #pragma unroll
            for (int ni = 0; ni < FN; ++ni) {
                int row = wn * FN * 16 + ni * 16 + lr;
                int off = row * 128 + ((((ks << 2) | kg) ^ (row & 7)) << 4);
                bh[ni] = *(const short8*)(sBhi + off);
                bl[ni] = *(const short8*)(sBlo + off);
            }
            #pragma unroll
            for (int mi = 0; mi < FM; ++mi)
                #pragma unroll
                for (int ni = 0; ni < FN; ++ni) {
                    acc[mi][ni] = __builtin_amdgcn_mfma_f32_16x16x32_bf16(ah[mi], bh[ni], acc[mi][ni], 0, 0, 0);
                    acc[mi][ni] = __builtin_amdgcn_mfma_f32_16x16x32_bf16(ah[mi], bl[ni], acc[mi][ni], 0, 0, 0);
                    acc[mi][ni] = __builtin_amdgcn_mfma_f32_16x16x32_bf16(al[mi], bh[ni], acc[mi][ni], 0, 0, 0);
                }
        }
        __syncthreads();
    }

    #pragma unroll
    for (int ni = 0; ni < FN; ++ni) {
        int col = n0 + wn * FN * 16 + ni * 16 + lr;
        float bb = bias[col];
        #pragma unroll
        for (int mi = 0; mi < FM; ++mi) {
            #pragma unroll
            for (int r = 0; r < 4; ++r) {
                int row = m0 + wm * FM * 16 + mi * 16 + kg * 4 + r;
                C[(size_t)row * INNER + col] = acc[mi][ni][r] + bb;
            }
        }
    }
}

// ---------- block reduce (sum, sumsq) over 256 threads ----------
__device__ inline void block_reduce2(float& s, float& sq, int tid) {
    #pragma unroll
    for (int off = 32; off > 0; off >>= 1) { s += __shfl_down(s, off); sq += __shfl_down(sq, off); }
    __shared__ float rs[4], rq[4];
    if ((tid & 63) == 0) { rs[tid >> 6] = s; rq[tid >> 6] = sq; }
    __syncthreads();
    s  = rs[0] + rs[1] + rs[2] + rs[3];
    sq = rq[0] + rq[1] + rq[2] + rq[3];
    __syncthreads();
}

// ---------- per-row LN stats over S1b rows of 3072 -> (mean, 1/denom) ----------
__global__ __launch_bounds__(256)
void ln_stats_v(const float* __restrict__ S1b, float* __restrict__ stat)
{
    const int row = blockIdx.x, tid = threadIdx.x;
    const float* p = S1b + (size_t)row * INNER;
    float s = 0.f, sq = 0.f;
    #pragma unroll
    for (int i = 0; i < 3; ++i) {
        float4 v = *(const float4*)(p + (tid + i * 256) * 4);
        s += v.x + v.y + v.z + v.w;
        sq += v.x*v.x + v.y*v.y + v.z*v.z + v.w*v.w;
    }
    block_reduce2(s, sq, tid);
    if (tid == 0) {
        float mean = s / (float)INNER;
        float var  = sq / (float)INNER - mean * mean;
        stat[row * 2 + 0] = mean;
        stat[row * 2 + 1] = 1.f / (sqrtf(var + EPSF) + EPSF);
    }
}

// ================= fused stepA: e2(t-1) -> LDS A-tile -> G1 (h @ Uzr^T) =================
// grid 256: nt = blk&31 (64-col n-tiles), mg = blk>>5 (32-row m-groups). Dynamic LDS 128KB.
__global__ __launch_bounds__(256)
void stepA(const float* __restrict__ s2prev, const float* __restrict__ s2p_prev,
           const float* __restrict__ candraw, const float* __restrict__ candpart,
           const float* __restrict__ hprev, float* __restrict__ hcur,
           const float* __restrict__ S1b, const float* __restrict__ stat,
           const float* __restrict__ gammas, const float* __restrict__ betas,
           const u16* __restrict__ Bzr_hi, const u16* __restrict__ Bzr_lo,
           float* __restrict__ s2cur, float* __restrict__ s2p_cur,
           float* __restrict__ out, int t)
{
    extern __shared__ char smem[];
    char* Ahi = smem;
    char* Alo = smem + 65536;
    __shared__ float stA[32][4];

    const int tid = threadIdx.x, blk = blockIdx.x;
    const int nt = blk & 31, mg = blk >> 5;
    const int m0 = mg * 32, n0 = nt * 64;

    if (t > 0) {
        {   // per-row stats from deterministic partials
            int row = tid >> 3, sl = tid & 7;
            float ss = 0.f, sq = 0.f, cs = 0.f, cq = 0.f;
            #pragma unroll
            for (int i = 0; i < 16; ++i) {
                int slot = sl + i * 8;
                ss += s2p_prev[((size_t)slot * B + m0 + row) * 2 + 0];
                sq += s2p_prev[((size_t)slot * B + m0 + row) * 2 + 1];
                if (i < 8) {
                    cs += candpart[((size_t)slot * B + m0 + row) * 2 + 0];
                    cq += candpart[((size_t)slot * B + m0 + row) * 2 + 1];
                }
            }
            #pragma unroll
            for (int m = 1; m < 8; m <<= 1) {
                ss += __shfl_xor(ss, m); sq += __shfl_xor(sq, m);
                cs += __shfl_xor(cs, m); cq += __shfl_xor(cq, m);
            }
            if (sl == 0) {
                float m2 = ss / 2048.f;
                stA[row][0] = m2;
                stA[row][1] = 1.f / (sqrtf(sq / 2048.f - m2 * m2 + EPSF) + EPSF);
                float mc = cs / 1024.f;
                stA[row][2] = mc;
                stA[row][3] = 1.f / (sqrtf(cq / 1024.f - mc * mc + EPSF) + EPSF);
            }
        }
        __syncthreads();

        const int k4 = tid * 4;
        const float4 g0z = *(const float4*)(gammas + k4);
        const float4 b0z = *(const float4*)(betas  + k4);
        const float4 g1z = *(const float4*)(gammas + INNER + k4);
        const float4 b1z = *(const float4*)(betas  + INNER + k4);
        const float4 g0c = *(const float4*)(gammas + NZ + k4);
        const float4 b0c = *(const float4*)(betas  + NZ + k4);
        const float4 g1c = *(const float4*)(gammas + INNER + NZ + k4);
        const float4 b1c = *(const float4*)(betas  + INNER + NZ + k4);
        const int jslot = k4 >> 3, sub = (tid & 1) * 8;

        #pragma unroll 2
        for (int it = 0; it < 32; ++it) {
            const int row = m0 + it;
            const size_t srow = (size_t)row * T + (t - 1);
            const float s1m = stat[srow * 2 + 0], s1r = stat[srow * 2 + 1];
            const float mean2 = stA[it][0], rden2 = stA[it][1];
            const float meanc = stA[it][2], rdenc = stA[it][3];
            float4 s2z = *(const float4*)(s2prev + (size_t)row * NZ + k4);
            float4 cr  = *(const float4*)(candraw + (size_t)row * H + k4);
            float4 s1z = *(const float4*)(S1b + srow * INNER + k4);
            float4 s1c = *(const float4*)(S1b + srow * INNER + NZ + k4);
            float4 hv  = *(const float4*)(hprev + (size_t)row * H + k4);
            const float* s2zp = (const float*)&s2z; const float* crp = (const float*)&cr;
            const float* s1zp = (const float*)&s1z; const float* s1cp = (const float*)&s1c;
            const float* hvp = (const float*)&hv;
            const float* g0zp = (const float*)&g0z; const float* b0zp = (const float*)&b0z;
            const float* g1zp = (const float*)&g1z; const float* b1zp = (const float*)&b1z;
            const float* g0cp = (const float*)&g0c; const float* b0cp = (const float*)&b0c;
            const float* g1cp = (const float*)&g1c; const float* b1cp = (const float*)&b1c;

            float hn[4];
            u16 hh[4], ll[4];
            #pragma unroll
            for (int q = 0; q < 4; ++q) {
                float zv = 0.2f * ((g0zp[q] * (s1zp[q] - s1m) * s1r + b0zp[q]) +
                                   (g1zp[q] * (s2zp[q] - mean2) * rden2 + b1zp[q])) + 0.5f;
                zv = fminf(fmaxf(zv, 0.f), 1.f);
                float cd = tanhf((g0cp[q] * (s1cp[q] - s1m) * s1r + b0cp[q]) +
                                 (g1cp[q] * (crp[q] - meanc) * rdenc + b1cp[q]));
                hn[q] = zv * hvp[q] + (1.f - zv) * cd;
                hh[q] = f2bf(hn[q]);
                ll[q] = f2bf(hn[q] - bf2f(hh[q]));
            }
            const int off = it * 2048 + ((jslot ^ (it & 7)) << 4) + sub;
            uint2 hp, lp;
            hp.x = (u32)hh[0] | ((u32)hh[1] << 16); hp.y = (u32)hh[2] | ((u32)hh[3] << 16);
            lp.x = (u32)ll[0] | ((u32)ll[1] << 16); lp.y = (u32)ll[2] | ((u32)ll[3] << 16);
            *(uint2*)(Ahi + off) = hp;
            *(uint2*)(Alo + off) = lp;
            if (nt == 0) {
                float4 ho; float* hop = (float*)&ho;
                hop[0] = hn[0]; hop[1] = hn[1]; hop[2] = hn[2]; hop[3] = hn[3];
                *(float4*)(hcur + (size_t)row * H + k4) = ho;
                *(float4*)(out + ((size_t)row * T + (t - 1)) * H + k4) = ho;
            }
        }
    } else {
        // t == 0: h(0) = 0 -> zero A-tile (h memset'd in preamble)
        uint4 zz = {0, 0, 0, 0};
        #pragma unroll
        for (int i = 0; i < 32; ++i)
            *(uint4*)(smem + tid * 16 + i * 4096) = zz;
    }
    __syncthreads();

    // G1: 4 waves = 1m x 4n, FM=2, FN=1. A from LDS (no barriers), B direct from global.
    const int wn = tid >> 6, lane = tid & 63;
    const int lr = lane & 15, kg = lane >> 4;
    f32x4 acc0 = {}, acc1 = {};
    const u16* bhp = Bzr_hi + (size_t)(n0 + wn * 16 + lr) * H;
    const u16* blp = Bzr_lo + (size_t)(n0 + wn * 16 + lr) * H;
    const int base0 = lr * 2048, base1 = (16 + lr) * 2048;
    const int xr = lr & 7;

    #pragma unroll 8
    for (int kc = 0; kc < 32; ++kc) {
        const int s = kc * 4 + kg;
        short8 bhv = *(const short8*)(bhp + s * 8);
        short8 blv = *(const short8*)(blp + s * 8);
        const int sw = (s ^ xr) << 4;
        short8 a0h = *(const short8*)(Ahi + base0 + sw);
        short8 a0l = *(const short8*)(Alo + base0 + sw);
        short8 a1h = *(const short8*)(Ahi + base1 + sw);
        short8 a1l = *(const short8*)(Alo + base1 + sw);
        acc0 = __builtin_amdgcn_mfma_f32_16x16x32_bf16(a0h, bhv, acc0, 0, 0, 0);
        acc0 = __builtin_amdgcn_mfma_f32_16x16x32_bf16(a0h, blv, acc0, 0, 0, 0);
        acc0 = __builtin_amdgcn_mfma_f32_16x16x32_bf16(a0l, bhv, acc0, 0, 0, 0);
        acc1 = __builtin_amdgcn_mfma_f32_16x16x32_bf16(a1h, bhv, acc1, 0, 0, 0);
        acc1 = __builtin_amdgcn_mfma_f32_16x16x32_bf16(a1h, blv, acc1, 0, 0, 0);
        acc1 = __builtin_amdgcn_mfma_f32_16x16x32_bf16(a1l, bhv, acc1, 0, 0, 0);
    }

    const int col = n0 + wn * 16 + lr;
    #pragma unroll
    for (int r = 0; r < 4; ++r) {
        s2cur[(size_t)(m0 + kg * 4 + r) * NZ + col]      = acc0[r];
        s2cur[(size_t)(m0 + 16 + kg * 4 + r) * NZ + col] = acc1[r];
    }
    const int slot = nt * 4 + wn;
    #pragma unroll
    for (int r = 0; r < 4; ++r) {
        float s0 = acc0[r], q0 = acc0[r] * acc0[r];
        float s1v = acc1[r], q1 = acc1[r] * acc1[r];
        #pragma unroll
        for (int m = 1; m < 16; m <<= 1) {
            s0 += __shfl_xor(s0, m); q0 += __shfl_xor(q0, m);
            s1v += __shfl_xor(s1v, m); q1 += __shfl_xor(q1, m);
        }
        if (lr == 0) {
            int row0 = m0 + kg * 4 + r, row1 = m0 + 16 + kg * 4 + r;
            s2p_cur[((size_t)slot * B + row0) * 2 + 0] = s0;
            s2p_cur[((size_t)slot * B + row0) * 2 + 1] = q0;
            s2p_cur[((size_t)slot * B + row1) * 2 + 0] = s1v;
            s2p_cur[((size_t)slot * B + row1) * 2 + 1] = q1;
        }
    }
}

// ================= fused stepB: e1-rh -> LDS A-tile -> G2 (rh @ Uc^T) =================
// grid 256: nt = blk&31 (32-col n-tiles), mg = blk>>5. Dynamic LDS 128KB.
__global__ __launch_bounds__(256)
void stepB(const float* __restrict__ s2cur, const float* __restrict__ s2p_cur,
           const float* __restrict__ hcur,
           const float* __restrict__ S1b, const float* __restrict__ stat,
           const float* __restrict__ gammas, const float* __restrict__ betas,
           const u16* __restrict__ Bc_hi, const u16* __restrict__ Bc_lo,
           float* __restrict__ candraw, float* __restrict__ candpart, int t)
{
    extern __shared__ char smem[];
    char* Ahi = smem;
    char* Alo = smem + 65536;
    __shared__ float stB[32][2];

    const int tid = threadIdx.x, blk = blockIdx.x;
    const int nt = blk & 31, mg = blk >> 5;
    const int m0 = mg * 32, n0 = nt * 32;

    {   // s2 row stats
        int row = tid >> 3, sl = tid & 7;
        float ss = 0.f, sq = 0.f;
        #pragma unroll
        for (int i = 0; i < 16; ++i) {
            int slot = sl + i * 8;
            ss += s2p_cur[((size_t)slot * B + m0 + row) * 2 + 0];
            sq += s2p_cur[((size_t)slot * B + m0 + row) * 2 + 1];
        }
        #pragma unroll
        for (int m = 1; m < 8; m <<= 1) { ss += __shfl_xor(ss, m); sq += __shfl_xor(sq, m); }
        if (sl == 0) {
            float m2 = ss / 2048.f;
            stB[row][0] = m2;
            stB[row][1] = 1.f / (sqrtf(sq / 2048.f - m2 * m2 + EPSF) + EPSF);
        }
    }
    __syncthreads();

    {   // rh for own 32 rows -> LDS split
        const int k4 = tid * 4;
        const float4 g0r = *(const float4*)(gammas + 1024 + k4);
        const float4 b0r = *(const float4*)(betas  + 1024 + k4);
        const float4 g1r = *(const float4*)(gammas + INNER + 1024 + k4);
        const float4 b1r = *(const float4*)(betas  + INNER + 1024 + k4);
        const int jslot = k4 >> 3, sub = (tid & 1) * 8;
        #pragma unroll 2
        for (int it = 0; it < 32; ++it) {
            const int row = m0 + it;
            const size_t srow = (size_t)row * T + t;
            const float s1m = stat[srow * 2 + 0], s1r = stat[srow * 2 + 1];
            const float mean2 = stB[it][0], rden2 = stB[it][1];
            float4 s2r  = *(const float4*)(s2cur + (size_t)row * NZ + 1024 + k4);
            float4 s1rv = *(const float4*)(S1b + srow * INNER + 1024 + k4);
            float4 hv   = *(const float4*)(hcur + (size_t)row * H + k4);
            const float* s2rp = (const float*)&s2r; const float* s1rp = (const float*)&s1rv;
            const float* hvp = (const float*)&hv;
            const float* g0rp = (const float*)&g0r; const float* b0rp = (const float*)&b0r;
            const float* g1rp = (const float*)&g1r; const float* b1rp = (const float*)&b1r;
            u16 hh[4], ll[4];
            #pragma unroll
            for (int q = 0; q < 4; ++q) {
                float rv = 0.2f * ((g0rp[q] * (s1rp[q] - s1m) * s1r + b0rp[q]) +
                                   (g1rp[q] * (s2rp[q] - mean2) * rden2 + b1rp[q])) + 0.5f;
                rv = fminf(fmaxf(rv, 0.f), 1.f);
                float rh = rv * hvp[q];
                hh[q] = f2bf(rh);
                ll[q] = f2bf(rh - bf2f(hh[q]));
            }
            const int off = it * 2048 + ((jslot ^ (it & 7)) << 4) + sub;
            uint2 hp, lp;
            hp.x = (u32)hh[0] | ((u32)hh[1] << 16); hp.y = (u32)hh[2] | ((u32)hh[3] << 16);
            lp.x = (u32)ll[0] | ((u32)ll[1] << 16); lp.y = (u32)ll[2] | ((u32)ll[3] << 16);
            *(uint2*)(Ahi + off) = hp;
            *(uint2*)(Alo + off) = lp;
        }
    }
    __syncthreads();

    // G2: 4 waves = 2m x 2n, FM=1, FN=1
    const int wid = tid >> 6, lane = tid & 63;
    const int wm = wid >> 1, wn = wid & 1;
    const int lr = lane & 15, kg = lane >> 4;
    f32x4 acc = {};
    const u16* bhp = Bc_hi + (size_t)(n0 + wn * 16 + lr) * H;
    const u16* blp = Bc_lo + (size_t)(n0 + wn * 16 + lr) * H;
    const int base = (wm * 16 + lr) * 2048;
    const int xr = lr & 7;

    #pragma unroll 8
    for (int kc = 0; kc < 32; ++kc) {
        const int s = kc * 4 + kg;
        short8 bhv = *(const short8*)(bhp + s * 8);
        short8 blv = *(const short8*)(blp + s * 8);
        const int sw = (s ^ xr) << 4;
        short8 ah = *(const short8*)(Ahi + base + sw);
        short8 al = *(const short8*)(Alo + base + sw);
        acc = __builtin_amdgcn_mfma_f32_16x16x32_bf16(ah, bhv, acc, 0, 0, 0);
        acc = __builtin_amdgcn_mfma_f32_16x16x32_bf16(ah, blv, acc, 0, 0, 0);
        acc = __builtin_amdgcn_mfma_f32_16x16x32_bf16(al, bhv, acc, 0, 0, 0);
    }

    const int col = n0 + wn * 16 + lr;
    #pragma unroll
    for (int r = 0; r < 4; ++r)
        candraw[(size_t)(m0 + wm * 16 + kg * 4 + r) * H + col] = acc[r];
    const int slot = nt * 2 + wn;
    #pragma unroll
    for (int r = 0; r < 4; ++r) {
        float s = acc[r], q = acc[r] * acc[r];
        #pragma unroll
        for (int m = 1; m < 16; m <<= 1) { s += __shfl_xor(s, m); q += __shfl_xor(q, m); }
        if (lr == 0) {
            int row = m0 + wm * 16 + kg * 4 + r;
            candpart[((size_t)slot * B + row) * 2 + 0] = s;
            candpart[((size_t)slot * B + row) * 2 + 1] = q;
        }
    }
}

// ---------- final e2: out[:, T-1] ----------
__global__ __launch_bounds__(256)
void final_e2(const float* __restrict__ s2cur, const float* __restrict__ s2p_cur,
              const float* __restrict__ candraw, const float* __restrict__ candpart,
              const float* __restrict__ hb, const float* __restrict__ S1b,
              const float* __restrict__ stat,
              const float* __restrict__ gammas, const float* __restrict__ betas,
              float* __restrict__ out)
{
    const int b = blockIdx.x, tid = threadIdx.x;
    __shared__ float st4[4];
    if (tid < 64) {
        float s = s2p_cur[((size_t)tid * B + b) * 2 + 0] + s2p_cur[((size_t)(tid + 64) * B + b) * 2 + 0];
        float q = s2p_cur[((size_t)tid * B + b) * 2 + 1] + s2p_cur[((size_t)(tid + 64) * B + b) * 2 + 1];
        #pragma unroll
        for (int m = 1; m < 64; m <<= 1) { s += __shfl_xor(s, m); q += __shfl_xor(q, m); }
        if (tid == 0) {
            float mean = s / (float)NZ;
            st4[0] = mean;
            st4[1] = 1.f / (sqrtf(q / (float)NZ - mean * mean + EPSF) + EPSF);
        }
    } else if (tid < 128) {
        int l = tid - 64;
        float s = candpart[((size_t)l * B + b) * 2 + 0];
        float q = candpart[((size_t)l * B + b) * 2 + 1];
        #pragma unroll
        for (int m = 1; m < 64; m <<= 1) { s += __shfl_xor(s, m); q += __shfl_xor(q, m); }
        if (l == 0) {
            float mean = s / (float)H;
            st4[2] = mean;
            st4[3] = 1.f / (sqrtf(q / (float)H - mean * mean + EPSF) + EPSF);
        }
    }
    __syncthreads();
    const float mean2 = st4[0], rden2 = st4[1], meanc = st4[2], rdenc = st4[3];

    const size_t srow = (size_t)b * T + (T - 1);
    const float s1m = stat[srow * 2 + 0], s1r = stat[srow * 2 + 1];
    const int j0 = tid * 4;
    float4 s2z = *(const float4*)(s2cur + (size_t)b * NZ + j0);
    float4 cr  = *(const float4*)(candraw + (size_t)b * H + j0);
    float4 s1z = *(const float4*)(S1b + srow * INNER + j0);
    float4 s1c = *(const float4*)(S1b + srow * INNER + NZ + j0);
    float4 hv  = *(const float4*)(hb + (size_t)b * H + j0);
    const float* s2zp = (const float*)&s2z; const float* crp = (const float*)&cr;
    const float* s1zp = (const float*)&s1z; const float* s1cp = (const float*)&s1c;
    const float* hvp = (const float*)&hv;
    float4 oo; float* op = (float*)&oo;
    #pragma unroll
    for (int q = 0; q < 4; ++q) {
        int j = j0 + q;
        float zv = 0.2f * ((gammas[j] * (s1zp[q] - s1m) * s1r + betas[j]) +
                           (gammas[INNER + j] * (s2zp[q] - mean2) * rden2 + betas[INNER + j])) + 0.5f;
        zv = fminf(fmaxf(zv, 0.f), 1.f);
        float cd = tanhf((gammas[NZ + j] * (s1cp[q] - s1m) * s1r + betas[NZ + j]) +
                         (gammas[INNER + NZ + j] * (crp[q] - meanc) * rdenc + betas[INNER + NZ + j]));
        op[q] = zv * hvp[q] + (1.f - zv) * cd;
    }
    *(float4*)(out + ((size_t)b * T + (T - 1)) * H + j0) = oo;
}

// ================= round-9 alternate step path (if big dynamic LDS unavailable) =================
template<int BM, int BN, int FM, int FN>
__global__ __launch_bounds__(256)
void step_gemm(const u16* __restrict__ Ahi, const u16* __restrict__ Alo,
               const u16* __restrict__ Bhi, const u16* __restrict__ Blo,
               float* __restrict__ C, int ldc)
{
    constexpr int NWN = BN / (FN * 16);
    constexpr int NCA = BM * 16 / 256;
    constexpr int NCB = BN * 16 / 256;
    __shared__ char lds[(BM + BN) * 512];
    char* sAhi = lds;
    char* sAlo = lds + BM * 256;
    char* sBhi = lds + BM * 512;
    char* sBlo = lds + BM * 512 + BN * 256;

    const int tid = threadIdx.x;
    const int m0 = blockIdx.y * BM, n0 = blockIdx.x * BN;
    const int wid = tid >> 6, lane = tid & 63;
    const int wm = wid / NWN, wn = wid % NWN;
    const int lr = lane & 15, kg = lane >> 4;

    f32x4 acc[FM][FN] = {};

    for (int k0 = 0; k0 < H; k0 += 128) {
        #pragma unroll
        for (int i = 0; i < NCA; ++i) {
            int c = tid + i * 256;
            int row = c >> 4, kc = c & 15;
            int boff = row * 256 + ((kc ^ (row & 7)) << 4);
            *(float4*)(sAhi + boff) = *(const float4*)(Ahi + (size_t)(m0 + row) * H + k0 + kc * 8);
            *(float4*)(sAlo + boff) = *(const float4*)(Alo + (size_t)(m0 + row) * H + k0 + kc * 8);
        }
        #pragma unroll
        for (int i = 0; i < NCB; ++i) {
            int c = tid + i * 256;
            int row = c >> 4, kc = c & 15;
            int boff = row * 256 + ((kc ^ (row & 7)) << 4);
            *(float4*)(sBhi + boff) = *(const float4*)(Bhi + (size_t)(n0 + row) * H + k0 + kc * 8);
            *(float4*)(sBlo + boff) = *(const float4*)(Blo + (size_t)(n0 + row) * H + k0 + kc * 8);
        }
        __syncthreads();

        #pragma unroll
        for (int ks = 0; ks < 4; ++ks) {
            short8 ah[FM], al[FM], bh[FN], bl[FN];
            #pragma unroll
            for (int mi = 0; mi < FM; ++mi) {
                int row = wm * FM * 16 + mi * 16 + lr;
                int off = row * 256 + ((((ks << 2) | kg) ^ (row & 7)) << 4);
                ah[mi] = *(const short8*)(sAhi + off);
                al[mi] = *(const short8*)(sAlo + off);
            }
            #pragma unroll
            for (int ni = 0; ni < FN; ++ni) {
                int row = wn * FN * 16 + ni * 16 + lr;
                int off = row * 256 + ((((ks << 2) | kg) ^ (row & 7)) << 4);
                bh[ni] = *(const short8*)(sBhi + off);
                bl[ni] = *(const short8*)(sBlo + off);
            }
            #pragma unroll
            for (int mi = 0; mi < FM; ++mi)
                #pragma unroll
                for (int ni = 0; ni < FN; ++ni) {
                    acc[mi][ni] = __builtin_amdgcn_mfma_f32_16x16x32_bf16(ah[mi], bh[ni], acc[mi][ni], 0, 0, 0);
                    acc[mi][ni] = __builtin_amdgcn_mfma_f32_16x16x32_bf16(ah[mi], bl[ni], acc[mi][ni], 0, 0, 0);
                    acc[mi][ni] = __builtin_amdgcn_mfma_f32_16x16x32_bf16(al[mi], bh[ni], acc[mi][ni], 0, 0, 0);
                }
        }
        __syncthreads();
    }

    #pragma unroll
    for (int mi = 0; mi < FM; ++mi)
        #pragma unroll
        for (int ni = 0; ni < FN; ++ni) {
            int col = n0 + wn * FN * 16 + ni * 16 + lr;
            #pragma unroll
            for (int r = 0; r < 4; ++r) {
                int row = m0 + wm * FM * 16 + mi * 16 + kg * 4 + r;
                C[(size_t)row * ldc + col] = acc[mi][ni][r];
            }
        }
}

__global__ __launch_bounds__(256)
void step_e1_v(const float* __restrict__ s2raw, const float* __restrict__ S1b,
               const float* __restrict__ stat, const float* __restrict__ h,
               const float* __restrict__ gammas, const float* __restrict__ betas,
               float* __restrict__ z, u16* __restrict__ rh_hi, u16* __restrict__ rh_lo, int t)
{
    const int b = blockIdx.x, tid = threadIdx.x;
    const float* row = s2raw + (size_t)b * NZ;
    float az[4], ar[4];
    {
        float4 vz = *(const float4*)(row + tid * 4);
        float4 vr = *(const float4*)(row + 1024 + tid * 4);
        az[0]=vz.x; az[1]=vz.y; az[2]=vz.z; az[3]=vz.w;
        ar[0]=vr.x; ar[1]=vr.y; ar[2]=vr.z; ar[3]=vr.w;
    }
    float s = 0.f, sq = 0.f;
    #pragma unroll
    for (int q = 0; q < 4; ++q) { s += az[q] + ar[q]; sq += az[q]*az[q] + ar[q]*ar[q]; }
    block_reduce2(s, sq, tid);
    const float mean = s / (float)NZ;
    const float var  = sq / (float)NZ - mean * mean;
    const float denom = sqrtf(var + EPSF) + EPSF;

    const size_t srow = (size_t)b * T + t;
    const float s1m = stat[srow * 2 + 0], s1r = stat[srow * 2 + 1];
    const float* s1 = S1b + srow * INNER;
    const int j0 = tid * 4;
    float4 zo;
    float* zp = (float*)&zo;
    #pragma unroll
    for (int q = 0; q < 4; ++q) {
        int j = j0 + q;
        float s1v = gammas[j] * (s1[j] - s1m) * s1r + betas[j];
        float ln  = gammas[INNER + j] * (az[q] - mean) / denom + betas[INNER + j];
        float sv  = 0.2f * (s1v + ln) + 0.5f;
        zp[q] = fminf(fmaxf(sv, 0.f), 1.f);
    }
    *(float4*)(z + (size_t)b * H + j0) = zo;

    uint2 hp, lp;
    u16 hh[4], ll[4];
    #pragma unroll
    for (int q = 0; q < 4; ++q) {
        int j = 1024 + j0 + q;
        float s1v = gammas[j] * (s1[j] - s1m) * s1r + betas[j];
        float ln  = gammas[INNER + j] * (ar[q] - mean) / denom + betas[INNER + j];
        float sv  = 0.2f * (s1v + ln) + 0.5f;
        sv = fminf(fmaxf(sv, 0.f), 1.f);
        float rv = sv * h[(size_t)b * H + j0 + q];
        hh[q] = f2bf(rv);
        ll[q] = f2bf(rv - bf2f(hh[q]));
    }
    hp.x = (u32)hh[0] | ((u32)hh[1] << 16); hp.y = (u32)hh[2] | ((u32)hh[3] << 16);
    lp.x = (u32)ll[0] | ((u32)ll[1] << 16); lp.y = (u32)ll[2] | ((u32)ll[3] << 16);
    *(uint2*)(rh_hi + (size_t)b * H + j0) = hp;
    *(uint2*)(rh_lo + (size_t)b * H + j0) = lp;
}

__global__ __launch_bounds__(256)
void step_e2_v(const float* __restrict__ candraw, const float* __restrict__ S1b,
               const float* __restrict__ stat,
               const float* __restrict__ gammas, const float* __restrict__ betas,
               const float* __restrict__ z, float* __restrict__ h,
               u16* __restrict__ h_hi, u16* __restrict__ h_lo,
               float* __restrict__ out, int t)
{
    const int b = blockIdx.x, tid = threadIdx.x;
    float a[4];
    {
        float4 v = *(const float4*)(candraw + (size_t)b * H + tid * 4);
        a[0]=v.x; a[1]=v.y; a[2]=v.z; a[3]=v.w;
    }
    float s = a[0]+a[1]+a[2]+a[3];
    float sq = a[0]*a[0]+a[1]*a[1]+a[2]*a[2]+a[3]*a[3];
    block_reduce2(s, sq, tid);
    const float mean = s / (float)H;
    const float var  = sq / (float)H - mean * mean;
    const float denom = sqrtf(var + EPSF) + EPSF;

    const size_t srow = (size_t)b * T + t;
    const float s1m = stat[srow * 2 + 0], s1r = stat[srow * 2 + 1];
    const float* s1 = S1b + srow * INNER + NZ;
    const int j0 = tid * 4;
    float4 ho;
    float* hp_ = (float*)&ho;
    u16 hh[4], ll[4];
    #pragma unroll
    for (int q = 0; q < 4; ++q) {
        int j = j0 + q;
        float s1v = gammas[NZ + j] * (s1[j] - s1m) * s1r + betas[NZ + j];
        float ln  = gammas[INNER + NZ + j] * (a[q] - mean) / denom + betas[INNER + NZ + j];
        float cand = tanhf(s1v + ln);
        float zz = z[(size_t)b * H + j];
        float hold = h[(size_t)b * H + j];
        float hn = zz * hold + (1.f - zz) * cand;
        hp_[q] = hn;
        hh[q] = f2bf(hn);
        ll[q] = f2bf(hn - bf2f(hh[q]));
    }
    *(float4*)(h + (size_t)b * H + j0) = ho;
    uint2 hpck, lpck;
    hpck.x = (u32)hh[0] | ((u32)hh[1] << 16); hpck.y = (u32)hh[2] | ((u32)hh[3] << 16);
    lpck.x = (u32)ll[0] | ((u32)ll[1] << 16); lpck.y = (u32)ll[2] | ((u32)ll[3] << 16);
    *(uint2*)(h_hi + (size_t)b * H + j0) = hpck;
    *(uint2*)(h_lo + (size_t)b * H + j0) = lpck;
    *(float4*)(out + ((size_t)b * T + t) * H + j0) = ho;
}

// ================= fp32 fallback (validated) =================
__global__ __launch_bounds__(256)
void ln_rows_v(float* __restrict__ S1, const float* __restrict__ bias,
               const float* __restrict__ gammas, const float* __restrict__ betas)
{
    const int row = blockIdx.x, tid = threadIdx.x;
    float* p = S1 + (size_t)row * INNER;
    float a[12];
    float s = 0.f, sq = 0.f;
    #pragma unroll
    for (int i = 0; i < 3; ++i) {
        int c = tid + i * 256;
        float4 v = *(const float4*)(p + c * 4);
        float4 bb = *(const float4*)(bias + c * 4);
        a[i*4+0] = v.x + bb.x; a[i*4+1] = v.y + bb.y; a[i*4+2] = v.z + bb.z; a[i*4+3] = v.w + bb.w;
        s += a[i*4+0] + a[i*4+1] + a[i*4+2] + a[i*4+3];
        sq += a[i*4+0]*a[i*4+0] + a[i*4+1]*a[i*4+1] + a[i*4+2]*a[i*4+2] + a[i*4+3]*a[i*4+3];
    }
    block_reduce2(s, sq, tid);
    const float mean = s / (float)INNER;
    const float var  = sq / (float)INNER - mean * mean;
    const float denom = sqrtf(var + EPSF) + EPSF;
    #pragma unroll
    for (int i = 0; i < 3; ++i) {
        int c = tid + i * 256;
        float4 o;
        o.x = gammas[c*4+0] * (a[i*4+0] - mean) / denom + betas[c*4+0];
        o.y = gammas[c*4+1] * (a[i*4+1] - mean) / denom + betas[c*4+1];
        o.z = gammas[c*4+2] * (a[i*4+2] - mean) / denom + betas[c*4+2];
        o.w = gammas[c*4+3] * (a[i*4+3] - mean) / denom + betas[c*4+3];
        *(float4*)(p + c * 4) = o;
    }
}

__global__ __launch_bounds__(256)
void gemm_fb(const float* __restrict__ A, int lda,
             const float* __restrict__ Bm, int ldb,
             float* __restrict__ C, int ldc, int K)
{
    constexpr int BM = 64, BN = 64, BK = 16;
    __shared__ float As[BK][BM];
    __shared__ float Bs[BK][BN];
    const int tid = threadIdx.x;
    const int tx = tid & 15, ty = tid >> 4;
    float acc[4][4] = {};
    const float* Ab = A + (size_t)blockIdx.y * BM * lda;
    const float* Bb = Bm + (size_t)blockIdx.x * BN;
    for (int k0 = 0; k0 < K; k0 += BK) {
        #pragma unroll
        for (int i = 0; i < 4; ++i) {
            int e = tid + i * 256; int m = e >> 4, k = e & 15;
            As[k][m] = Ab[(size_t)m * lda + k0 + k];
        }
        #pragma unroll
        for (int i = 0; i < 4; ++i) {
            int e = tid + i * 256; int k = e >> 6, n = e & 63;
            Bs[k][n] = Bb[(size_t)(k0 + k) * ldb + n];
        }
        __syncthreads();
        #pragma unroll
        for (int k = 0; k < BK; ++k) {
            float av[4], bv[4];
            #pragma unroll
            for (int i = 0; i < 4; ++i) av[i] = As[k][ty * 4 + i];
            #pragma unroll
            for (int j = 0; j < 4; ++j) bv[j] = Bs[k][tx * 4 + j];
            #pragma unroll
            for (int i = 0; i < 4; ++i)
                #pragma unroll
                for (int j = 0; j < 4; ++j)
                    acc[i][j] = fmaf(av[i], bv[j], acc[i][j]);
        }
        __syncthreads();
    }
    const int row0 = blockIdx.y * BM + ty * 4;
    const int col0 = blockIdx.x * BN + tx * 4;
    #pragma unroll
    for (int i = 0; i < 4; ++i)
        #pragma unroll
        for (int j = 0; j < 4; ++j)
            C[(size_t)(row0 + i) * ldc + col0 + j] = acc[i][j];
}

__global__ __launch_bounds__(256)
void step_e1_fb(const float* __restrict__ s2raw, const float* __restrict__ S1,
                const float* __restrict__ h,
                const float* __restrict__ gammas, const float* __restrict__ betas,
                float* __restrict__ z, float* __restrict__ rh, int t)
{
    const int b = blockIdx.x, tid = threadIdx.x;
    const float* row = s2raw + (size_t)b * NZ;
    float v[8]; float s = 0.f, sq = 0.f;
    #pragma unroll
    for (int i = 0; i < 8; ++i) { v[i] = row[tid + i * 256]; s += v[i]; sq += v[i]*v[i]; }
    block_reduce2(s, sq, tid);
    const float mean = s / (float)NZ;
    const float var  = sq / (float)NZ - mean * mean;
    const float denom = sqrtf(var + EPSF) + EPSF;
    const float* s1 = S1 + (size_t)(b * T + t) * INNER;
    #pragma unroll
    for (int i = 0; i < 8; ++i) {
        int j = tid + i * 256;
        float ln = gammas[INNER + j] * (v[i] - mean) / denom + betas[INNER + j];
        float sv = 0.2f * (s1[j] + ln) + 0.5f;
        sv = fminf(fmaxf(sv, 0.f), 1.f);
        if (j < H) z[(size_t)b * H + j] = sv;
        else       rh[(size_t)b * H + (j - H)] = sv * h[(size_t)b * H + (j - H)];
    }
}

__global__ __launch_bounds__(256)
void step_e2_fb(const float* __restrict__ candraw, const float* __restrict__ S1,
                const float* __restrict__ gammas, const float* __restrict__ betas,
                const float* __restrict__ z, float* __restrict__ h,
                float* __restrict__ out, int t)
{
    const int b = blockIdx.x, tid = threadIdx.x;
    float v[4]; float s = 0.f, sq = 0.f;
    #pragma unroll
    for (int i = 0; i < 4; ++i) { v[i] = candraw[(size_t)b * H + tid + i * 256]; s += v[i]; sq += v[i]*v[i]; }
    block_reduce2(s, sq, tid);
    const float mean = s / (float)H;
    const float var  = sq / (float)H - mean * mean;
    const float denom = sqrtf(var + EPSF) + EPSF;
    const float* s1 = S1 + (size_t)(b * T + t) * INNER + NZ;
    #pragma unroll
    for (int i = 0; i < 4; ++i) {
        int j = tid + i * 256;
        float ln = gammas[INNER + NZ + j] * (v[i] - mean) / denom + betas[INNER + NZ + j];
        float cand = tanhf(s1[j] + ln);
        float zz = z[(size_t)b * H + j];
        float hold = h[(size_t)b * H + j];
        float hn = zz * hold + (1.f - zz) * cand;
        h[(size_t)b * H + j] = hn;
        out[((size_t)b * T + t) * H + j] = hn;
    }
}

// ================= launch =================
extern "C" void kernel_launch(void* const* d_in, const int* in_sizes, int n_in,
                              void* d_out, int out_size, void* d_ws, size_t ws_size,
                              hipStream_t stream) {
    const float* x      = (const float*)d_in[0];
    const float* W      = (const float*)d_in[1];
    const float* U      = (const float*)d_in[2];
    const float* bias   = (const float*)d_in[3];
    const float* gammas = (const float*)d_in[4];
    const float* betas  = (const float*)d_in[5];
    float* out = (float*)d_out;
    (void)in_sizes; (void)n_in; (void)out_size;

    char* ws = (char*)d_ws;
    size_t off = 0;
    auto alloc = [&](size_t bytes) { void* p = ws + off; off += (bytes + 255) & ~(size_t)255; return p; };

    const size_t sz_S1  = (size_t)BT * INNER * 4;   // 402.7 MB
    const size_t sz_T_  = (size_t)INNER * H * 2;    // 6.29 MB per split half
    const size_t sz_st  = (size_t)BT * 2 * 4;       // 256 KB
    const size_t sz_pool = 14 * 1024 * 1024;        // transient pool (WT splits / step buffers)
    const size_t need_new = sz_S1 + 2 * sz_T_ + sz_st + sz_pool + 64 * 1024;

    if (ws_size >= need_new) {
        float* S1b  = (float*)alloc(sz_S1);
        u16* UT_hi  = (u16*)alloc(sz_T_);
        u16* UT_lo  = (u16*)alloc(sz_T_);
        float* stat = (float*)alloc(sz_st);
        char* pool  = (char*)alloc(sz_pool);

        // preamble uses pool for W-transpose splits
        u16* WT_hi = (u16*)pool;
        u16* WT_lo = (u16*)(pool + ((sz_T_ + 255) & ~(size_t)255));

        transpose_split<<<dim3(INNER / 32, H / 32), 256, 0, stream>>>(W, WT_hi, WT_lo);
        transpose_split<<<dim3(INNER / 32, H / 32), 256, 0, stream>>>(U, UT_hi, UT_lo);
        gemm_s1<<<dim3(INNER / 128, BT / 128), 256, 0, stream>>>(x, WT_hi, WT_lo, bias, S1b);
        ln_stats_v<<<BT, 256, 0, stream>>>(S1b, stat);

        // carve step buffers from pool (WT no longer needed)
        size_t po = 0;
        auto palloc = [&](size_t bytes) { void* p = pool + po; po += (bytes + 255) & ~(size_t)255; return p; };
        float* hb0      = (float*)palloc((size_t)B * H * 4);
        float* hb1      = (float*)palloc((size_t)B * H * 4);
        float* s2b0     = (float*)palloc((size_t)B * NZ * 4);
        float* s2b1     = (float*)palloc((size_t)B * NZ * 4);
        float* candraw  = (float*)palloc((size_t)B * H * 4);
        float* s2p0     = (float*)palloc((size_t)128 * B * 2 * 4);
        float* s2p1     = (float*)palloc((size_t)128 * B * 2 * 4);
        float* candpart = (float*)palloc((size_t)64 * B * 2 * 4);
        float* hb[2]  = { hb0, hb1 };
        float* s2b[2] = { s2b0, s2b1 };
        float* s2p[2] = { s2p0, s2p1 };

        hipMemsetAsync(hb0, 0, (size_t)B * H * 4, stream);

        const u16* Uc_hi = UT_hi + (size_t)NZ * H;
        const u16* Uc_lo = UT_lo + (size_t)NZ * H;

        const int LDSB = 131072;
        bool big =
            hipFuncSetAttribute((const void*)stepA, hipFuncAttributeMaxDynamicSharedMemorySize, LDSB) == hipSuccess &&
            hipFuncSetAttribute((const void*)stepB, hipFuncAttributeMaxDynamicSharedMemorySize, LDSB) == hipSuccess;

        if (big) {
            for (int t = 0; t < T; ++t) {
                const int cur = t & 1, prv = cur ^ 1;
                stepA<<<256, 256, LDSB, stream>>>(
                    s2b[prv], s2p[prv], candraw, candpart,
                    hb[prv], hb[cur], S1b, stat, gammas, betas,
                    UT_hi, UT_lo, s2b[cur], s2p[cur], out, t);
                stepB<<<256, 256, LDSB, stream>>>(
                    s2b[cur], s2p[cur], hb[cur], S1b, stat, gammas, betas,
                    Uc_hi, Uc_lo, candraw, candpart, t);
            }
            const int last = (T - 1) & 1;
            final_e2<<<256, 256, 0, stream>>>(
                s2b[last], s2p[last], candraw, candpart, hb[last],
                S1b, stat, gammas, betas, out);
        } else {
            // round-9 validated 4-dispatch path (buffers re-carved from pool)
            po = 0;
            float* h     = (float*)palloc((size_t)B * H * 4);
            float* z     = (float*)palloc((size_t)B * H * 4);
            float* s2raw = (float*)palloc((size_t)B * NZ * 4);
            float* craw  = (float*)palloc((size_t)B * H * 4);
            u16* h_hi    = (u16*)palloc((size_t)B * H * 2);
            u16* h_lo    = (u16*)palloc((size_t)B * H * 2);
            u16* rh_hi   = (u16*)palloc((size_t)B * H * 2);
            u16* rh_lo   = (u16*)palloc((size_t)B * H * 2);
            hipMemsetAsync(h,    0, (size_t)B * H * 4, stream);
            hipMemsetAsync(h_hi, 0, (size_t)B * H * 2, stream);
            hipMemsetAsync(h_lo, 0, (size_t)B * H * 2, stream);
            for (int t = 0; t < T; ++t) {
                step_gemm<32, 64, 1, 2><<<dim3(NZ / 64, B / 32), 256, 0, stream>>>(
                    h_hi, h_lo, UT_hi, UT_lo, s2raw, NZ);
                step_e1_v<<<B, 256, 0, stream>>>(s2raw, S1b, stat, h, gammas, betas,
                                                 z, rh_hi, rh_lo, t);
                step_gemm<32, 32, 1, 1><<<dim3(H / 32, B / 32), 256, 0, stream>>>(
                    rh_hi, rh_lo, Uc_hi, Uc_lo, craw, H);
                step_e2_v<<<B, 256, 0, stream>>>(craw, S1b, stat, gammas, betas,
                                                 z, h, h_hi, h_lo, out, t);
            }
        }
    } else {
        // fp32 fallback
        float* S1    = (float*)alloc(sz_S1);
        float* h     = (float*)alloc((size_t)B * H * 4);
        float* z     = (float*)alloc((size_t)B * H * 4);
        float* rh    = (float*)alloc((size_t)B * H * 4);
        float* s2raw = (float*)alloc((size_t)B * NZ * 4);
        float* candraw = (float*)alloc((size_t)B * H * 4);

        hipMemsetAsync(h, 0, (size_t)B * H * 4, stream);
        gemm_fb<<<dim3(INNER / 64, BT / 64), 256, 0, stream>>>(x, H, W, INNER, S1, INNER, H);
        ln_rows_v<<<BT, 256, 0, stream>>>(S1, bias, gammas, betas);
        for (int t = 0; t < T; ++t) {
            gemm_fb<<<dim3(NZ / 64, B / 64), 256, 0, stream>>>(h, H, U, INNER, s2raw, NZ, H);
            step_e1_fb<<<B, 256, 0, stream>>>(s2raw, S1, h, gammas, betas, z, rh, t);
            gemm_fb<<<dim3(H / 64, B / 64), 256, 0, stream>>>(rh, H, U + NZ, INNER, candraw, H, H);
            step_e2_fb<<<B, 256, 0, stream>>>(candraw, S1, gammas, betas, z, h, out, t);
        }
    }
}

// Round 11
// 5117.254 us; speedup vs baseline: 2.1315x; 2.1315x over previous
//
#include <hip/hip_runtime.h>
#include <hip/hip_bf16.h>

#define EPSF 1e-5f

typedef unsigned short u16;
typedef unsigned int   u32;
typedef __attribute__((ext_vector_type(8))) short short8;
typedef __attribute__((ext_vector_type(4))) float f32x4;

constexpr int B  = 256;
constexpr int T  = 128;
constexpr int H  = 1024;
constexpr int INNER = 3 * H;   // 3072
constexpr int BT = B * T;      // 32768
constexpr int NZ = 2 * H;      // 2048

__device__ inline u16 f2bf(float v) {
    u32 u = __float_as_uint(v);
    return (u16)((u + 0x7fffu + ((u >> 16) & 1u)) >> 16);
}
__device__ inline float bf2f(u16 h) { return __uint_as_float(((u32)h) << 16); }

// ---------- one-time: transpose fp32 [1024][3072] -> split bf16 [3072][1024] ----------
__global__ __launch_bounds__(256)
void transpose_split(const float* __restrict__ src, u16* __restrict__ dhi, u16* __restrict__ dlo)
{
    __shared__ float tile[32][33];
    const int tx = threadIdx.x & 31, ty = threadIdx.x >> 5;
    const int bx = blockIdx.x, by = blockIdx.y;
    #pragma unroll
    for (int i = 0; i < 4; ++i)
        tile[ty + i * 8][tx] = src[(size_t)(by * 32 + ty + i * 8) * INNER + bx * 32 + tx];
    __syncthreads();
    #pragma unroll
    for (int i = 0; i < 4; ++i) {
        int n = bx * 32 + ty + i * 8;
        int k = by * 32 + tx;
        float v = tile[tx][ty + i * 8];
        u16 hi = f2bf(v);
        dhi[(size_t)n * H + k] = hi;
        dlo[(size_t)n * H + k] = f2bf(v - bf2f(hi));
    }
}

// ---------- big GEMM: S1b = x @ W + bias (fp32 out), split-bf16 3-pass MFMA ----------
__global__ __launch_bounds__(256)
void gemm_s1(const float* __restrict__ Af,
             const u16* __restrict__ Bhi, const u16* __restrict__ Blo,
             const float* __restrict__ bias, float* __restrict__ C)
{
    constexpr int BM = 128, BN = 128, FM = 4, FN = 4;
    __shared__ char lds[(BM + BN) * 256];
    char* sAhi = lds;
    char* sAlo = lds + BM * 128;
    char* sBhi = lds + BM * 256;
    char* sBlo = lds + BM * 256 + BN * 128;

    const int tid = threadIdx.x;
    const int m0 = blockIdx.y * BM, n0 = blockIdx.x * BN;
    const int wid = tid >> 6, lane = tid & 63;
    const int wm = wid >> 1, wn = wid & 1;
    const int lr = lane & 15, kg = lane >> 4;

    f32x4 acc[FM][FN] = {};

    for (int k0 = 0; k0 < H; k0 += 64) {
        {
            constexpr int NC = BM * 16 / 256;
            #pragma unroll
            for (int i = 0; i < NC; ++i) {
                int c = tid + i * 256;
                int row = c >> 4, kc = c & 15;
                const float4 v = *(const float4*)(Af + (size_t)(m0 + row) * H + k0 + kc * 4);
                u16 h0 = f2bf(v.x), h1 = f2bf(v.y), h2 = f2bf(v.z), h3 = f2bf(v.w);
                u16 l0 = f2bf(v.x - bf2f(h0)), l1 = f2bf(v.y - bf2f(h1));
                u16 l2 = f2bf(v.z - bf2f(h2)), l3 = f2bf(v.w - bf2f(h3));
                uint2 hp, lp;
                hp.x = (u32)h0 | ((u32)h1 << 16); hp.y = (u32)h2 | ((u32)h3 << 16);
                lp.x = (u32)l0 | ((u32)l1 << 16); lp.y = (u32)l2 | ((u32)l3 << 16);
                int boff = row * 128 + ((((kc >> 1)) ^ (row & 7)) << 4) + ((kc & 1) << 3);
                *(uint2*)(sAhi + boff) = hp;
                *(uint2*)(sAlo + boff) = lp;
            }
        }
        {
            constexpr int NC = BN * 8 / 256;
            #pragma unroll
            for (int i = 0; i < NC; ++i) {
                int c = tid + i * 256;
                int row = c >> 3, kc = c & 7;
                int boff = row * 128 + ((kc ^ (row & 7)) << 4);
                *(float4*)(sBhi + boff) = *(const float4*)(Bhi + (size_t)(n0 + row) * H + k0 + kc * 8);
                *(float4*)(sBlo + boff) = *(const float4*)(Blo + (size_t)(n0 + row) * H + k0 + kc * 8);
            }
        }
        __syncthreads();

        #pragma unroll
        for (int ks = 0; ks < 2; ++ks) {
            short8 ah[FM], al[FM], bh[FN], bl[FN];
            #pragma unroll
            for (int mi = 0; mi < FM; ++mi) {
                int row = wm * FM * 16 + mi * 16 + lr;
                int off = row * 128 + ((((ks << 2) | kg) ^ (row & 7)) << 4);
                ah[mi] = *(const short8*)(sAhi + off);
                al[mi] = *(const short8*)(sAlo + off);
            }
            #pragma unroll
            for (int ni = 0; ni < FN; ++ni) {
                int row = wn * FN * 16 + ni * 16 + lr;
                int off = row * 128 + ((((ks << 2) | kg) ^ (row & 7)) << 4);
                bh[ni] = *(const short8*)(sBhi + off);
                bl[ni] = *(const short8*)(sBlo + off);
            }
            #pragma unroll
            for (int mi = 0; mi < FM; ++mi)
                #pragma unroll
                for (int ni = 0; ni < FN; ++ni) {
                    acc[mi][ni] = __builtin_amdgcn_mfma_f32_16x16x32_bf16(ah[mi], bh[ni], acc[mi][ni], 0, 0, 0);
                    acc[mi][ni] = __builtin_amdgcn_mfma_f32_16x16x32_bf16(ah[mi], bl[ni], acc[mi][ni], 0, 0, 0);
                    acc[mi][ni] = __builtin_amdgcn_mfma_f32_16x16x32_bf16(al[mi], bh[ni], acc[mi][ni], 0, 0, 0);
                }
        }
        __syncthreads();
    }

    #pragma unroll
    for (int ni = 0; ni < FN; ++ni) {
        int col = n0 + wn * FN * 16 + ni * 16 + lr;
        float bb = bias[col];
        #pragma unroll
        for (int mi = 0; mi < FM; ++mi) {
            #pragma unroll
            for (int r = 0; r < 4; ++r) {
                int row = m0 + wm * FM * 16 + mi * 16 + kg * 4 + r;
                C[(size_t)row * INNER + col] = acc[mi][ni][r] + bb;
            }
        }
    }
}

// ---------- pipaged step GEMM, BK=128 (half the barriers of BK=64), plain staging ----------
// 2D grid: blockIdx.x = n-tile, blockIdx.y = m-tile.
template<int BM, int BN, int FM, int FN>
__global__ __launch_bounds__(256)
void step_gemm(const u16* __restrict__ Ahi, const u16* __restrict__ Alo,
               const u16* __restrict__ Bhi, const u16* __restrict__ Blo,
               float* __restrict__ C, int ldc)
{
    constexpr int NWN = BN / (FN * 16);
    constexpr int NWM = BM / (FM * 16);
    static_assert(NWM * NWN == 4, "need 4 waves");
    constexpr int NCA = BM * 16 / 256;
    constexpr int NCB = BN * 16 / 256;
    __shared__ char lds[(BM + BN) * 512];
    char* sAhi = lds;
    char* sAlo = lds + BM * 256;
    char* sBhi = lds + BM * 512;
    char* sBlo = lds + BM * 512 + BN * 256;

    const int tid = threadIdx.x;
    const int m0 = blockIdx.y * BM, n0 = blockIdx.x * BN;
    const int wid = tid >> 6, lane = tid & 63;
    const int wm = wid / NWN, wn = wid % NWN;
    const int lr = lane & 15, kg = lane >> 4;

    f32x4 acc[FM][FN] = {};

    for (int k0 = 0; k0 < H; k0 += 128) {
        #pragma unroll
        for (int i = 0; i < NCA; ++i) {
            int c = tid + i * 256;
            int row = c >> 4, kc = c & 15;
            int boff = row * 256 + ((kc ^ (row & 7)) << 4);
            *(float4*)(sAhi + boff) = *(const float4*)(Ahi + (size_t)(m0 + row) * H + k0 + kc * 8);
            *(float4*)(sAlo + boff) = *(const float4*)(Alo + (size_t)(m0 + row) * H + k0 + kc * 8);
        }
        #pragma unroll
        for (int i = 0; i < NCB; ++i) {
            int c = tid + i * 256;
            int row = c >> 4, kc = c & 15;
            int boff = row * 256 + ((kc ^ (row & 7)) << 4);
            *(float4*)(sBhi + boff) = *(const float4*)(Bhi + (size_t)(n0 + row) * H + k0 + kc * 8);
            *(float4*)(sBlo + boff) = *(const float4*)(Blo + (size_t)(n0 + row) * H + k0 + kc * 8);
        }
        __syncthreads();

        #pragma unroll
        for (int ks = 0; ks < 4; ++ks) {
            short8 ah[FM], al[FM], bh[FN], bl[FN];
            #pragma unroll
            for (int mi = 0; mi < FM; ++mi) {
                int row = wm * FM * 16 + mi * 16 + lr;
                int off = row * 256 + ((((ks << 2) | kg) ^ (row & 7)) << 4);
                ah[mi] = *(const short8*)(sAhi + off);
                al[mi] = *(const short8*)(sAlo + off);
            }
            #pragma unroll
            for (int ni = 0; ni < FN; ++ni) {
                int row = wn * FN * 16 + ni * 16 + lr;
                int off = row * 256 + ((((ks << 2) | kg) ^ (row & 7)) << 4);
                bh[ni] = *(const short8*)(sBhi + off);
                bl[ni] = *(const short8*)(sBlo + off);
            }
            #pragma unroll
            for (int mi = 0; mi < FM; ++mi)
                #pragma unroll
                for (int ni = 0; ni < FN; ++ni) {
                    acc[mi][ni] = __builtin_amdgcn_mfma_f32_16x16x32_bf16(ah[mi], bh[ni], acc[mi][ni], 0, 0, 0);
                    acc[mi][ni] = __builtin_amdgcn_mfma_f32_16x16x32_bf16(ah[mi], bl[ni], acc[mi][ni], 0, 0, 0);
                    acc[mi][ni] = __builtin_amdgcn_mfma_f32_16x16x32_bf16(al[mi], bh[ni], acc[mi][ni], 0, 0, 0);
                }
        }
        __syncthreads();
    }

    #pragma unroll
    for (int mi = 0; mi < FM; ++mi)
        #pragma unroll
        for (int ni = 0; ni < FN; ++ni) {
            int col = n0 + wn * FN * 16 + ni * 16 + lr;
            #pragma unroll
            for (int r = 0; r < 4; ++r) {
                int row = m0 + wm * FM * 16 + mi * 16 + kg * 4 + r;
                C[(size_t)row * ldc + col] = acc[mi][ni][r];
            }
        }
}

// ---------- block reduce (sum, sumsq) over 256 threads ----------
__device__ inline void block_reduce2(float& s, float& sq, int tid) {
    #pragma unroll
    for (int off = 32; off > 0; off >>= 1) { s += __shfl_down(s, off); sq += __shfl_down(sq, off); }
    __shared__ float rs[4], rq[4];
    if ((tid & 63) == 0) { rs[tid >> 6] = s; rq[tid >> 6] = sq; }
    __syncthreads();
    s  = rs[0] + rs[1] + rs[2] + rs[3];
    sq = rq[0] + rq[1] + rq[2] + rq[3];
    __syncthreads();
}

// ---------- per-row LN stats over S1b rows of 3072 -> (mean, 1/denom) ----------
__global__ __launch_bounds__(256)
void ln_stats_v(const float* __restrict__ S1b, float* __restrict__ stat)
{
    const int row = blockIdx.x, tid = threadIdx.x;
    const float* p = S1b + (size_t)row * INNER;
    float s = 0.f, sq = 0.f;
    #pragma unroll
    for (int i = 0; i < 3; ++i) {
        float4 v = *(const float4*)(p + (tid + i * 256) * 4);
        s += v.x + v.y + v.z + v.w;
        sq += v.x*v.x + v.y*v.y + v.z*v.z + v.w*v.w;
    }
    block_reduce2(s, sq, tid);
    if (tid == 0) {
        float mean = s / (float)INNER;
        float var  = sq / (float)INNER - mean * mean;
        stat[row * 2 + 0] = mean;
        stat[row * 2 + 1] = 1.f / (sqrtf(var + EPSF) + EPSF);
    }
}

// ---------- step elementwise 1: LN(s2raw, 2048) + inline S1 LN -> z fp32, rh split ----------
__global__ __launch_bounds__(256)
void step_e1_v(const float* __restrict__ s2raw, const float* __restrict__ S1b,
               const float* __restrict__ stat, const float* __restrict__ h,
               const float* __restrict__ gammas, const float* __restrict__ betas,
               float* __restrict__ z, u16* __restrict__ rh_hi, u16* __restrict__ rh_lo, int t)
{
    const int b = blockIdx.x, tid = threadIdx.x;
    const float* row = s2raw + (size_t)b * NZ;
    float az[4], ar[4];
    {
        float4 vz = *(const float4*)(row + tid * 4);
        float4 vr = *(const float4*)(row + 1024 + tid * 4);
        az[0]=vz.x; az[1]=vz.y; az[2]=vz.z; az[3]=vz.w;
        ar[0]=vr.x; ar[1]=vr.y; ar[2]=vr.z; ar[3]=vr.w;
    }
    float s = 0.f, sq = 0.f;
    #pragma unroll
    for (int q = 0; q < 4; ++q) { s += az[q] + ar[q]; sq += az[q]*az[q] + ar[q]*ar[q]; }
    block_reduce2(s, sq, tid);
    const float mean = s / (float)NZ;
    const float var  = sq / (float)NZ - mean * mean;
    const float denom = sqrtf(var + EPSF) + EPSF;

    const size_t srow = (size_t)b * T + t;
    const float s1m = stat[srow * 2 + 0], s1r = stat[srow * 2 + 1];
    const float* s1 = S1b + srow * INNER;
    const int j0 = tid * 4;
    float4 zo;
    float* zp = (float*)&zo;
    #pragma unroll
    for (int q = 0; q < 4; ++q) {
        int j = j0 + q;
        float s1v = gammas[j] * (s1[j] - s1m) * s1r + betas[j];
        float ln  = gammas[INNER + j] * (az[q] - mean) / denom + betas[INNER + j];
        float sv  = 0.2f * (s1v + ln) + 0.5f;
        zp[q] = fminf(fmaxf(sv, 0.f), 1.f);
    }
    *(float4*)(z + (size_t)b * H + j0) = zo;

    uint2 hp, lp;
    u16 hh[4], ll[4];
    #pragma unroll
    for (int q = 0; q < 4; ++q) {
        int j = 1024 + j0 + q;
        float s1v = gammas[j] * (s1[j] - s1m) * s1r + betas[j];
        float ln  = gammas[INNER + j] * (ar[q] - mean) / denom + betas[INNER + j];
        float sv  = 0.2f * (s1v + ln) + 0.5f;
        sv = fminf(fmaxf(sv, 0.f), 1.f);
        float rv = sv * h[(size_t)b * H + j0 + q];
        hh[q] = f2bf(rv);
        ll[q] = f2bf(rv - bf2f(hh[q]));
    }
    hp.x = (u32)hh[0] | ((u32)hh[1] << 16); hp.y = (u32)hh[2] | ((u32)hh[3] << 16);
    lp.x = (u32)ll[0] | ((u32)ll[1] << 16); lp.y = (u32)ll[2] | ((u32)ll[3] << 16);
    *(uint2*)(rh_hi + (size_t)b * H + j0) = hp;
    *(uint2*)(rh_lo + (size_t)b * H + j0) = lp;
}

// ---------- step elementwise 2: LN(candraw, 1024) + inline S1 LN -> tanh -> h update ----------
__global__ __launch_bounds__(256)
void step_e2_v(const float* __restrict__ candraw, const float* __restrict__ S1b,
               const float* __restrict__ stat,
               const float* __restrict__ gammas, const float* __restrict__ betas,
               const float* __restrict__ z, float* __restrict__ h,
               u16* __restrict__ h_hi, u16* __restrict__ h_lo,
               float* __restrict__ out, int t)
{
    const int b = blockIdx.x, tid = threadIdx.x;
    float a[4];
    {
        float4 v = *(const float4*)(candraw + (size_t)b * H + tid * 4);
        a[0]=v.x; a[1]=v.y; a[2]=v.z; a[3]=v.w;
    }
    float s = a[0]+a[1]+a[2]+a[3];
    float sq = a[0]*a[0]+a[1]*a[1]+a[2]*a[2]+a[3]*a[3];
    block_reduce2(s, sq, tid);
    const float mean = s / (float)H;
    const float var  = sq / (float)H - mean * mean;
    const float denom = sqrtf(var + EPSF) + EPSF;

    const size_t srow = (size_t)b * T + t;
    const float s1m = stat[srow * 2 + 0], s1r = stat[srow * 2 + 1];
    const float* s1 = S1b + srow * INNER + NZ;
    const int j0 = tid * 4;
    float4 ho;
    float* hp_ = (float*)&ho;
    u16 hh[4], ll[4];
    #pragma unroll
    for (int q = 0; q < 4; ++q) {
        int j = j0 + q;
        float s1v = gammas[NZ + j] * (s1[j] - s1m) * s1r + betas[NZ + j];
        float ln  = gammas[INNER + NZ + j] * (a[q] - mean) / denom + betas[INNER + NZ + j];
        float cand = tanhf(s1v + ln);
        float zz = z[(size_t)b * H + j];
        float hold = h[(size_t)b * H + j];
        float hn = zz * hold + (1.f - zz) * cand;
        hp_[q] = hn;
        hh[q] = f2bf(hn);
        ll[q] = f2bf(hn - bf2f(hh[q]));
    }
    *(float4*)(h + (size_t)b * H + j0) = ho;
    uint2 hpck, lpck;
    hpck.x = (u32)hh[0] | ((u32)hh[1] << 16); hpck.y = (u32)hh[2] | ((u32)hh[3] << 16);
    lpck.x = (u32)ll[0] | ((u32)ll[1] << 16); lpck.y = (u32)ll[2] | ((u32)ll[3] << 16);
    *(uint2*)(h_hi + (size_t)b * H + j0) = hpck;
    *(uint2*)(h_lo + (size_t)b * H + j0) = lpck;
    *(float4*)(out + ((size_t)b * T + t) * H + j0) = ho;
}

// ================= fallback (validated fp32 path) =================
__global__ __launch_bounds__(256)
void ln_rows_v(float* __restrict__ S1, const float* __restrict__ bias,
               const float* __restrict__ gammas, const float* __restrict__ betas)
{
    const int row = blockIdx.x, tid = threadIdx.x;
    float* p = S1 + (size_t)row * INNER;
    float a[12];
    float s = 0.f, sq = 0.f;
    #pragma unroll
    for (int i = 0; i < 3; ++i) {
        int c = tid + i * 256;
        float4 v = *(const float4*)(p + c * 4);
        float4 bb = *(const float4*)(bias + c * 4);
        a[i*4+0] = v.x + bb.x; a[i*4+1] = v.y + bb.y; a[i*4+2] = v.z + bb.z; a[i*4+3] = v.w + bb.w;
        s += a[i*4+0] + a[i*4+1] + a[i*4+2] + a[i*4+3];
        sq += a[i*4+0]*a[i*4+0] + a[i*4+1]*a[i*4+1] + a[i*4+2]*a[i*4+2] + a[i*4+3]*a[i*4+3];
    }
    block_reduce2(s, sq, tid);
    const float mean = s / (float)INNER;
    const float var  = sq / (float)INNER - mean * mean;
    const float denom = sqrtf(var + EPSF) + EPSF;
    #pragma unroll
    for (int i = 0; i < 3; ++i) {
        int c = tid + i * 256;
        float4 o;
        o.x = gammas[c*4+0] * (a[i*4+0] - mean) / denom + betas[c*4+0];
        o.y = gammas[c*4+1] * (a[i*4+1] - mean) / denom + betas[c*4+1];
        o.z = gammas[c*4+2] * (a[i*4+2] - mean) / denom + betas[c*4+2];
        o.w = gammas[c*4+3] * (a[i*4+3] - mean) / denom + betas[c*4+3];
        *(float4*)(p + c * 4) = o;
    }
}

__global__ __launch_bounds__(256)
void gemm_fb(const float* __restrict__ A, int lda,
             const float* __restrict__ Bm, int ldb,
             float* __restrict__ C, int ldc, int K)
{
    constexpr int BM = 64, BN = 64, BK = 16;
    __shared__ float As[BK][BM];
    __shared__ float Bs[BK][BN];
    const int tid = threadIdx.x;
    const int tx = tid & 15, ty = tid >> 4;
    float acc[4][4] = {};
    const float* Ab = A + (size_t)blockIdx.y * BM * lda;
    const float* Bb = Bm + (size_t)blockIdx.x * BN;
    for (int k0 = 0; k0 < K; k0 += BK) {
        #pragma unroll
        for (int i = 0; i < 4; ++i) {
            int e = tid + i * 256; int m = e >> 4, k = e & 15;
            As[k][m] = Ab[(size_t)m * lda + k0 + k];
        }
        #pragma unroll
        for (int i = 0; i < 4; ++i) {
            int e = tid + i * 256; int k = e >> 6, n = e & 63;
            Bs[k][n] = Bb[(size_t)(k0 + k) * ldb + n];
        }
        __syncthreads();
        #pragma unroll
        for (int k = 0; k < BK; ++k) {
            float av[4], bv[4];
            #pragma unroll
            for (int i = 0; i < 4; ++i) av[i] = As[k][ty * 4 + i];
            #pragma unroll
            for (int j = 0; j < 4; ++j) bv[j] = Bs[k][tx * 4 + j];
            #pragma unroll
            for (int i = 0; i < 4; ++i)
                #pragma unroll
                for (int j = 0; j < 4; ++j)
                    acc[i][j] = fmaf(av[i], bv[j], acc[i][j]);
        }
        __syncthreads();
    }
    const int row0 = blockIdx.y * BM + ty * 4;
    const int col0 = blockIdx.x * BN + tx * 4;
    #pragma unroll
    for (int i = 0; i < 4; ++i)
        #pragma unroll
        for (int j = 0; j < 4; ++j)
            C[(size_t)(row0 + i) * ldc + col0 + j] = acc[i][j];
}

__global__ __launch_bounds__(256)
void step_e1_fb(const float* __restrict__ s2raw, const float* __restrict__ S1,
                const float* __restrict__ h,
                const float* __restrict__ gammas, const float* __restrict__ betas,
                float* __restrict__ z, float* __restrict__ rh, int t)
{
    const int b = blockIdx.x, tid = threadIdx.x;
    const float* row = s2raw + (size_t)b * NZ;
    float v[8]; float s = 0.f, sq = 0.f;
    #pragma unroll
    for (int i = 0; i < 8; ++i) { v[i] = row[tid + i * 256]; s += v[i]; sq += v[i]*v[i]; }
    block_reduce2(s, sq, tid);
    const float mean = s / (float)NZ;
    const float var  = sq / (float)NZ - mean * mean;
    const float denom = sqrtf(var + EPSF) + EPSF;
    const float* s1 = S1 + (size_t)(b * T + t) * INNER;
    #pragma unroll
    for (int i = 0; i < 8; ++i) {
        int j = tid + i * 256;
        float ln = gammas[INNER + j] * (v[i] - mean) / denom + betas[INNER + j];
        float sv = 0.2f * (s1[j] + ln) + 0.5f;
        sv = fminf(fmaxf(sv, 0.f), 1.f);
        if (j < H) z[(size_t)b * H + j] = sv;
        else       rh[(size_t)b * H + (j - H)] = sv * h[(size_t)b * H + (j - H)];
    }
}

__global__ __launch_bounds__(256)
void step_e2_fb(const float* __restrict__ candraw, const float* __restrict__ S1,
                const float* __restrict__ gammas, const float* __restrict__ betas,
                const float* __restrict__ z, float* __restrict__ h,
                float* __restrict__ out, int t)
{
    const int b = blockIdx.x, tid = threadIdx.x;
    float v[4]; float s = 0.f, sq = 0.f;
    #pragma unroll
    for (int i = 0; i < 4; ++i) { v[i] = candraw[(size_t)b * H + tid + i * 256]; s += v[i]; sq += v[i]*v[i]; }
    block_reduce2(s, sq, tid);
    const float mean = s / (float)H;
    const float var  = sq / (float)H - mean * mean;
    const float denom = sqrtf(var + EPSF) + EPSF;
    const float* s1 = S1 + (size_t)(b * T + t) * INNER + NZ;
    #pragma unroll
    for (int i = 0; i < 4; ++i) {
        int j = tid + i * 256;
        float ln = gammas[INNER + NZ + j] * (v[i] - mean) / denom + betas[INNER + NZ + j];
        float cand = tanhf(s1[j] + ln);
        float zz = z[(size_t)b * H + j];
        float hold = h[(size_t)b * H + j];
        float hn = zz * hold + (1.f - zz) * cand;
        h[(size_t)b * H + j] = hn;
        out[((size_t)b * T + t) * H + j] = hn;
    }
}

// ================= launch =================
extern "C" void kernel_launch(void* const* d_in, const int* in_sizes, int n_in,
                              void* d_out, int out_size, void* d_ws, size_t ws_size,
                              hipStream_t stream) {
    const float* x      = (const float*)d_in[0];
    const float* W      = (const float*)d_in[1];
    const float* U      = (const float*)d_in[2];
    const float* bias   = (const float*)d_in[3];
    const float* gammas = (const float*)d_in[4];
    const float* betas  = (const float*)d_in[5];
    float* out = (float*)d_out;
    (void)in_sizes; (void)n_in; (void)out_size;

    char* ws = (char*)d_ws;
    size_t off = 0;
    auto alloc = [&](size_t bytes) { void* p = ws + off; off += (bytes + 255) & ~(size_t)255; return p; };

    const size_t sz_S1 = (size_t)BT * INNER * 4;          // 402.7 MB
    const size_t sz_T  = (size_t)INNER * H * 2;           // 6.29 MB per split half
    const size_t sz_st = (size_t)BT * 2 * 4;              // 256 KB
    const size_t need_new = sz_S1 + 4 * sz_T + sz_st + ((size_t)B * H * 4) * 3 + (size_t)B * NZ * 4
                          + ((size_t)B * H * 2) * 4 + 16 * 1024;   // ~435.5 MB

    if (ws_size >= need_new) {
        float* S1b   = (float*)alloc(sz_S1);
        u16* WT_hi   = (u16*)alloc(sz_T);
        u16* WT_lo   = (u16*)alloc(sz_T);
        u16* UT_hi   = (u16*)alloc(sz_T);
        u16* UT_lo   = (u16*)alloc(sz_T);
        float* stat  = (float*)alloc(sz_st);
        float* h     = (float*)alloc((size_t)B * H * 4);
        float* z     = (float*)alloc((size_t)B * H * 4);
        float* s2raw = (float*)alloc((size_t)B * NZ * 4);
        float* candraw = (float*)alloc((size_t)B * H * 4);
        u16* h_hi    = (u16*)alloc((size_t)B * H * 2);
        u16* h_lo    = (u16*)alloc((size_t)B * H * 2);
        u16* rh_hi   = (u16*)alloc((size_t)B * H * 2);
        u16* rh_lo   = (u16*)alloc((size_t)B * H * 2);

        transpose_split<<<dim3(INNER / 32, H / 32), 256, 0, stream>>>(W, WT_hi, WT_lo);
        transpose_split<<<dim3(INNER / 32, H / 32), 256, 0, stream>>>(U, UT_hi, UT_lo);

        // S1b = x @ W + bias (raw, pre-LN); per-row stats separately; LN applied inline in e1/e2
        gemm_s1<<<dim3(INNER / 128, BT / 128), 256, 0, stream>>>(x, WT_hi, WT_lo, bias, S1b);
        ln_stats_v<<<BT, 256, 0, stream>>>(S1b, stat);

        hipMemsetAsync(h,    0, (size_t)B * H * 4, stream);
        hipMemsetAsync(h_hi, 0, (size_t)B * H * 2, stream);
        hipMemsetAsync(h_lo, 0, (size_t)B * H * 2, stream);

        const u16* Uc_hi = UT_hi + (size_t)NZ * H;
        const u16* Uc_lo = UT_lo + (size_t)NZ * H;

        for (int t = 0; t < T; ++t) {
            // G1: s2raw = h @ Uzr^T   (32x64 tiles, grid (32,8), BK=128)
            step_gemm<32, 64, 1, 2><<<dim3(NZ / 64, B / 32), 256, 0, stream>>>(
                h_hi, h_lo, UT_hi, UT_lo, s2raw, NZ);
            step_e1_v<<<B, 256, 0, stream>>>(s2raw, S1b, stat, h, gammas, betas,
                                             z, rh_hi, rh_lo, t);
            // G2: candraw = rh @ Uc^T (32x32 tiles, grid (32,8), BK=128)
            step_gemm<32, 32, 1, 1><<<dim3(H / 32, B / 32), 256, 0, stream>>>(
                rh_hi, rh_lo, Uc_hi, Uc_lo, candraw, H);
            step_e2_v<<<B, 256, 0, stream>>>(candraw, S1b, stat, gammas, betas,
                                             z, h, h_hi, h_lo, out, t);
        }
    } else {
        // fallback: validated fp32 path
        float* S1    = (float*)alloc(sz_S1);
        float* h     = (float*)alloc((size_t)B * H * 4);
        float* z     = (float*)alloc((size_t)B * H * 4);
        float* rh    = (float*)alloc((size_t)B * H * 4);
        float* s2raw = (float*)alloc((size_t)B * NZ * 4);
        float* candraw = (float*)alloc((size_t)B * H * 4);

        hipMemsetAsync(h, 0, (size_t)B * H * 4, stream);
        gemm_fb<<<dim3(INNER / 64, BT / 64), 256, 0, stream>>>(x, H, W, INNER, S1, INNER, H);
        ln_rows_v<<<BT, 256, 0, stream>>>(S1, bias, gammas, betas);
        for (int t = 0; t < T; ++t) {
            gemm_fb<<<dim3(NZ / 64, B / 64), 256, 0, stream>>>(h, H, U, INNER, s2raw, NZ, H);
            step_e1_fb<<<B, 256, 0, stream>>>(s2raw, S1, h, gammas, betas, z, rh, t);
            gemm_fb<<<dim3(H / 64, B / 64), 256, 0, stream>>>(rh, H, U + NZ, INNER, candraw, H, H);
            step_e2_fb<<<B, 256, 0, stream>>>(candraw, S1, gammas, betas, z, h, out, t);
        }
    }
}